// Round 11
// baseline (1221.328 us; speedup 1.0000x reference)
//
#include <hip/hip_runtime.h>

#define IN_DIM 18
#define XPAD 20     // IN_DIM padded to 5 float4 slots
#define HID 64
#define EMB 32
#define PSHIFT 7    // 128 nodes per partition
#define PN 128
#define PMAXP 800   // max partitions (N <= 102400)
#define BCAP 16     // k_part per-tile LDS bin capacity (mean ~5 @ TILE 4096)
#define TILE 4096
#define CSH 14      // src-chunk shift: 16384 nodes -> xn chunk 1.3MB, hn2 2.1MB
#define NCMAX 8

typedef int vint4 __attribute__((ext_vector_type(4)));
typedef unsigned int u32;

// ---------------- zero counters ----------------

__global__ void k_zero(int* __restrict__ gcnt, int m) {
    int i = blockIdx.x * 256 + threadIdx.x;
    if (i < m) gcnt[i] = 0;
}

// ---------------- bucketing: edges -> per-partition buckets (u32 packed) -----
// pack: (src << 7) | (dst & 127); partition = dst >> 7

__global__ void k_part(const int* __restrict__ src, const int* __restrict__ dst,
                       int* __restrict__ gcnt, u32* __restrict__ gbuf,
                       int e, int Pp, int cap) {
    __shared__ u32 sbuf[PMAXP][BCAP];
    __shared__ int scnt[PMAXP];
    __shared__ int sbase[PMAXP];
    int tid = threadIdx.x;
    int ntile = (e + TILE - 1) / TILE;
    for (int tile = blockIdx.x; tile < ntile; tile += gridDim.x) {
        for (int p = tid; p < Pp; p += 256) scnt[p] = 0;
        __syncthreads();
#pragma unroll
        for (int r = 0; r < TILE / 1024; ++r) {
            int i = tile * TILE + (r * 256 + tid) * 4;
            if (i + 4 <= e) {
                vint4 s4 = __builtin_nontemporal_load((const vint4*)(src + i));
                vint4 d4 = __builtin_nontemporal_load((const vint4*)(dst + i));
#pragma unroll
                for (int k = 0; k < 4; ++k) {
                    int d = d4[k];
                    int p = d >> PSHIFT;
                    u32 pr = ((u32)s4[k] << PSHIFT) | (u32)(d & (PN - 1));
                    int pos = atomicAdd(&scnt[p], 1);
                    if (pos < BCAP) sbuf[p][pos] = pr;
                    else {
                        int gp = atomicAdd(&gcnt[p], 1);
                        __builtin_nontemporal_store(pr, &gbuf[(size_t)p * cap + gp]);
                    }
                }
            } else if (i < e) {
                for (int k = i; k < e; ++k) {
                    int d = dst[k];
                    int p = d >> PSHIFT;
                    u32 pr = ((u32)src[k] << PSHIFT) | (u32)(d & (PN - 1));
                    int pos = atomicAdd(&scnt[p], 1);
                    if (pos < BCAP) sbuf[p][pos] = pr;
                    else {
                        int gp = atomicAdd(&gcnt[p], 1);
                        __builtin_nontemporal_store(pr, &gbuf[(size_t)p * cap + gp]);
                    }
                }
            }
        }
        __syncthreads();
        for (int p = tid; p < Pp; p += 256)
            sbase[p] = atomicAdd(&gcnt[p], min(scnt[p], BCAP));
        __syncthreads();
        int wid = tid >> 6, lane = tid & 63;
        for (int p = wid; p < Pp; p += 4) {
            int c = min(scnt[p], BCAP);
            int b = sbase[p];
            for (int k = lane; k < c; k += 64)
                __builtin_nontemporal_store(sbuf[p][k], &gbuf[(size_t)p * cap + b + k]);
        }
        __syncthreads();
    }
}

// ---------------- per-partition: deg->dis + src-chunk counting sort ----------

__global__ void k_build4(const u32* __restrict__ gbuf, const int* __restrict__ gcnt,
                         float* __restrict__ dis, int* __restrict__ segoff,
                         u32* __restrict__ pairs2, int cap, int n, int nchunk,
                         int doSeg) {
    __shared__ int sdeg[PN];
    __shared__ int scc[NCMAX];
    __shared__ int sbs[NCMAX + 1];
    __shared__ int swp[NCMAX];
    int p = blockIdx.x;
    int tid = threadIdx.x;
    int lo = p << PSHIFT;
    int nn = min(n - lo, PN);
    int cnt = gcnt[p];
    const u32* buf = gbuf + (size_t)p * cap;

    if (tid < PN) sdeg[tid] = 0;
    if (tid < NCMAX) { scc[tid] = 0; swp[tid] = 0; }
    __syncthreads();
    for (int k = tid; k < cnt; k += 256) {
        u32 pr = __builtin_nontemporal_load(&buf[k]);
        atomicAdd(&sdeg[pr & (PN - 1)], 1);
        if (doSeg) atomicAdd(&scc[pr >> (PSHIFT + CSH)], 1);
    }
    __syncthreads();
    if (tid == 0) {
        int* so = segoff + p * (NCMAX + 1);
        if (doSeg) {
            int r = 0;
            for (int c = 0; c < nchunk; ++c) { sbs[c] = r; so[c] = r; r += scc[c]; }
            sbs[nchunk] = r; so[nchunk] = r;
        } else {
            so[0] = 0; so[1] = cnt;
        }
    }
    if (tid < nn) dis[lo + tid] = rsqrtf((float)(sdeg[tid] + 1));  // +1 self-loop
    __syncthreads();
    if (doSeg) {
        for (int k = tid; k < cnt; k += 256) {
            u32 pr = __builtin_nontemporal_load(&buf[k]);
            int c = pr >> (PSHIFT + CSH);
            int pos = sbs[c] + atomicAdd(&swp[c], 1);
            pairs2[(size_t)p * cap + pos] = pr;
        }
    }
}

// ---------------- xn = x * dis, padded to 20 floats ----------------

__global__ void k_xn(const float* __restrict__ x, const float* __restrict__ dis,
                     float* __restrict__ xn, int n) {
    int gid = blockIdx.x * 256 + threadIdx.x;
    if (gid >= n * 5) return;
    int i = gid / 5, s = gid - (gid / 5) * 5;
    float dn = dis[i];
    const float* xr = x + (size_t)i * IN_DIM;
    float4 v;
    int k = s * 4;
    v.x = (k + 0 < IN_DIM) ? xr[k + 0] * dn : 0.f;
    v.y = (k + 1 < IN_DIM) ? xr[k + 1] * dn : 0.f;
    v.z = (k + 2 < IN_DIM) ? xr[k + 2] * dn : 0.f;
    v.w = (k + 3 < IN_DIM) ? xr[k + 3] * dn : 0.f;
    *(float4*)(xn + (size_t)i * XPAD + k) = v;
}

// ---------------- layer 1: edge-parallel LDS scatter + W1/relu/W2 epilogue ---
// Block per partition. Edge phase: 12 edges/wave x 5 lanes x float4, x2 unroll
// (full MLP regardless of node degree); src-chunk segments keep xn L2-resident.

__global__ void k_sc1(const float* __restrict__ xn, const u32* __restrict__ prs,
                      const int* __restrict__ segoff, const float* __restrict__ dis,
                      const float* __restrict__ W1, const float* __restrict__ b1,
                      const float* __restrict__ W2, float* __restrict__ hn2,
                      int cap, int n, int nseg) {
    __shared__ float sagg[PN * XPAD];   // 10 KB accumulators
    __shared__ float sw[IN_DIM * HID];
    __shared__ float sw2[HID * EMB];
    __shared__ float sb[HID];
    __shared__ float sh[4][HID];
    int tid = threadIdx.x;
    for (int t = tid; t < IN_DIM * HID; t += 256) sw[t] = W1[t];
    for (int t = tid; t < HID * EMB; t += 256) sw2[t] = W2[t];
    if (tid < HID) sb[tid] = b1[tid];
    for (int t = tid; t < PN * XPAD; t += 256) sagg[t] = 0.f;
    __syncthreads();

    int p = blockIdx.x;
    int lo = p << PSHIFT;
    int nn = min(n - lo, PN);
    const u32* pp = prs + (size_t)p * cap;
    const int* so = segoff + p * (NCMAX + 1);
    int wv = tid >> 6, lane = tid & 63;
    int eg = lane / 5;
    int sl = lane - eg * 5;
    bool act = eg < 12;

    for (int c = 0; c < nseg; ++c) {
        int s0 = so[c], s1 = so[c + 1];
        for (int base = s0 + wv * 24; base < s1; base += 96) {
            int i0 = base + eg;
            if (act && i0 < s1) {
                u32 pr = pp[i0];
                int dl = pr & (PN - 1);
                float4 v = *(const float4*)(xn + (size_t)(pr >> PSHIFT) * XPAD + sl * 4);
                float* d = &sagg[dl * XPAD + sl * 4];
                atomicAdd(d + 0, v.x); atomicAdd(d + 1, v.y);
                atomicAdd(d + 2, v.z); atomicAdd(d + 3, v.w);
            }
            int i1 = base + 12 + eg;
            if (act && i1 < s1) {
                u32 pr = pp[i1];
                int dl = pr & (PN - 1);
                float4 v = *(const float4*)(xn + (size_t)(pr >> PSHIFT) * XPAD + sl * 4);
                float* d = &sagg[dl * XPAD + sl * 4];
                atomicAdd(d + 0, v.x); atomicAdd(d + 1, v.y);
                atomicAdd(d + 2, v.z); atomicAdd(d + 3, v.w);
            }
        }
    }
    __syncthreads();

    // epilogue: per node -> +self, x dis, W1+bias+relu, W2, x dis
    for (int nd = wv; nd < nn; nd += 4) {
        int node = lo + nd;
        float dn = dis[node];
        if (lane < 5) {
            float4 v = *(const float4*)(xn + (size_t)node * XPAD + lane * 4);
            float* d = &sagg[nd * XPAD + lane * 4];
            d[0] += v.x; d[1] += v.y; d[2] += v.z; d[3] += v.w;
        }
        float s = 0.f;
#pragma unroll
        for (int k = 0; k < IN_DIM; ++k) s += sagg[nd * XPAD + k] * sw[k * HID + lane];
        float hv = dn * s + sb[lane];
        sh[wv][lane] = hv > 0.f ? hv : 0.f;
        int g = lane & 31, half = lane >> 5;
        float s2 = 0.f;
#pragma unroll
        for (int k = 0; k < 32; ++k)
            s2 += sh[wv][half * 32 + k] * sw2[(half * 32 + k) * EMB + g];
        s2 += __shfl_xor(s2, 32);
        if (half == 0) hn2[(size_t)node * EMB + g] = dn * s2;
    }
}

// ---------------- layer 2: edge-parallel LDS scatter + finalize --------------
// 8 edges/wave x 8 lanes x float4, x2 unroll.

__global__ void k_sc2(const float* __restrict__ hn2, const u32* __restrict__ prs,
                      const int* __restrict__ segoff, const float* __restrict__ dis,
                      const float* __restrict__ b2, float* __restrict__ z,
                      int cap, int n, int nseg) {
    __shared__ float sagg[PN * EMB];    // 16 KB
    __shared__ float sb2[EMB];
    int tid = threadIdx.x;
    if (tid < EMB) sb2[tid] = b2[tid];
    for (int t = tid; t < PN * EMB; t += 256) sagg[t] = 0.f;
    __syncthreads();

    int p = blockIdx.x;
    int lo = p << PSHIFT;
    int nn = min(n - lo, PN);
    const u32* pp = prs + (size_t)p * cap;
    const int* so = segoff + p * (NCMAX + 1);
    int wv = tid >> 6, lane = tid & 63;
    int eg = lane >> 3;
    int sl = lane & 7;

    for (int c = 0; c < nseg; ++c) {
        int s0 = so[c], s1 = so[c + 1];
        for (int base = s0 + wv * 16; base < s1; base += 64) {
            int i0 = base + eg;
            if (i0 < s1) {
                u32 pr = pp[i0];
                int dl = pr & (PN - 1);
                float4 v = *(const float4*)(hn2 + (size_t)(pr >> PSHIFT) * EMB + sl * 4);
                float* d = &sagg[dl * EMB + sl * 4];
                atomicAdd(d + 0, v.x); atomicAdd(d + 1, v.y);
                atomicAdd(d + 2, v.z); atomicAdd(d + 3, v.w);
            }
            int i1 = base + 8 + eg;
            if (i1 < s1) {
                u32 pr = pp[i1];
                int dl = pr & (PN - 1);
                float4 v = *(const float4*)(hn2 + (size_t)(pr >> PSHIFT) * EMB + sl * 4);
                float* d = &sagg[dl * EMB + sl * 4];
                atomicAdd(d + 0, v.x); atomicAdd(d + 1, v.y);
                atomicAdd(d + 2, v.z); atomicAdd(d + 3, v.w);
            }
        }
    }
    __syncthreads();

    for (int idx = tid; idx < nn * EMB; idx += 256) {
        int nd = idx >> 5, g = idx & 31;
        int node = lo + nd;
        float dn = dis[node];
        z[(size_t)node * EMB + g] =
            dn * (sagg[idx] + hn2[(size_t)node * EMB + g]) + sb2[g];
    }
}

// ---------------- pair head ----------------

__global__ void k_head(const float* __restrict__ z, const int* __restrict__ tg,
                       const float* __restrict__ Wo, const float* __restrict__ bo,
                       float* __restrict__ out, int btot) {
    int i = blockIdx.x * 256 + threadIdx.x;
    if (i >= btot) return;
    int t0 = tg[i], t1 = tg[btot + i];
    const float* z0 = z + (size_t)t0 * EMB;
    const float* z1 = z + (size_t)t1 * EMB;
    float acc = 0.f;
#pragma unroll
    for (int g = 0; g < EMB; ++g) acc += z0[g] * z1[g] * Wo[g];
    out[i] = acc + bo[0];
}

// ---------------- launch ----------------

extern "C" void kernel_launch(void* const* d_in, const int* in_sizes, int n_in,
                              void* d_out, int out_size, void* d_ws, size_t ws_size,
                              hipStream_t stream) {
    const float* x  = (const float*)d_in[0];
    const int*   ei = (const int*)d_in[1];
    const int*   tg = (const int*)d_in[2];
    const float* W1 = (const float*)d_in[3];
    const float* b1 = (const float*)d_in[4];
    const float* W2 = (const float*)d_in[5];
    const float* b2 = (const float*)d_in[6];
    const float* Wo = (const float*)d_in[7];
    const float* bo = (const float*)d_in[8];
    float* out = (float*)d_out;

    int n = in_sizes[0] / IN_DIM;
    int e = in_sizes[1] / 2;
    int b = in_sizes[2] / 2;
    const int* src = ei;
    const int* dst = ei + e;

    char* ws = (char*)d_ws;
    size_t off = 0;
    auto alloc = [&](size_t bytes) -> char* {
        char* p = ws + off;
        off += (bytes + 255) & ~(size_t)255;
        return p;
    };
    float* dis    = (float*)alloc((size_t)n * 4);
    float* xn     = (float*)alloc((size_t)n * XPAD * 4);
    float* hn2    = (float*)alloc((size_t)n * EMB * 4);
    float* z      = (float*)alloc((size_t)n * EMB * 4);
    int*   gcnt   = (int*)alloc(PMAXP * 4);
    int*   segoff = (int*)alloc((size_t)PMAXP * (NCMAX + 1) * 4);

    int Pp = (n + PN - 1) >> PSHIFT;
    int nchunk = min((n + (1 << CSH) - 1) >> CSH, NCMAX);
    int meanb = e / (Pp > 0 ? Pp : 1);
    int cap = meanb + meanb / 8 + 256;
    size_t gbytes = (size_t)Pp * cap * 4;

    u32* gbuf = (u32*)alloc(gbytes);
    bool doSeg = (off + gbytes + 256) <= ws_size;
    u32* pairs2 = (u32*)alloc(gbytes);

    k_zero<<<(PMAXP + 255) / 256, 256, 0, stream>>>(gcnt, PMAXP);
    k_part<<<512, 256, 0, stream>>>(src, dst, gcnt, gbuf, e, Pp, cap);
    k_build4<<<Pp, 256, 0, stream>>>(gbuf, gcnt, dis, segoff, pairs2, cap, n,
                                     nchunk, doSeg ? 1 : 0);
    k_xn<<<((size_t)n * 5 + 255) / 256, 256, 0, stream>>>(x, dis, xn, n);

    const u32* prs = doSeg ? pairs2 : gbuf;
    int nseg = doSeg ? nchunk : 1;
    k_sc1<<<Pp, 256, 0, stream>>>(xn, prs, segoff, dis, W1, b1, W2, hn2, cap, n, nseg);
    k_sc2<<<Pp, 256, 0, stream>>>(hn2, prs, segoff, dis, b2, z, cap, n, nseg);

    k_head<<<(b + 255) / 256, 256, 0, stream>>>(z, tg, Wo, bo, out, b);
}

// Round 12
// 233.301 us; speedup vs baseline: 5.2350x; 5.2350x over previous
//
#include <hip/hip_runtime.h>

#define IN_DIM 18
#define XPAD 20     // IN_DIM padded to 5 float4 slots
#define HID 64
#define EMB 32
#define NGROUP 8    // legacy fallback partitioning
#define PSHIFT 9    // 512 nodes per partition
#define PMAX 200    // LDS arrays sized for <=200 partitions (N<=102400)
#define BCAP 80     // k_part per-tile LDS bin capacity (u32 pairs)
#define TILE 4096
#define SCAP 16896  // k_build LDS pair-staging capacity
#define NPB 16      // nodes per block in k_agg1f (weight-staging amortization)

typedef int vint4 __attribute__((ext_vector_type(4)));
typedef unsigned int u32;

__device__ inline float4 shfl_f4(float4 v, int srcLane) {
    float4 r;
    r.x = __shfl(v.x, srcLane);
    r.y = __shfl(v.y, srcLane);
    r.z = __shfl(v.z, srcLane);
    r.w = __shfl(v.w, srcLane);
    return r;
}

__device__ inline float4 shfl_xor_f4(float4 v, int m) {
    v.x = __shfl_xor(v.x, m);
    v.y = __shfl_xor(v.y, m);
    v.z = __shfl_xor(v.z, m);
    v.w = __shfl_xor(v.w, m);
    return v;
}

// ---------------- init ----------------

__global__ void k_init(int* __restrict__ deg, int* __restrict__ gcnt, int n) {
    int i = blockIdx.x * 256 + threadIdx.x;
    if (i < n) deg[i] = 1;          // legacy path
    if (i < 256) gcnt[i] = 0;
}

// ---------------- bucketing: (dst,src) -> P dst-partition buckets ----------
// pair packed as u32: (src << 9) | (dst & 511)   [requires n < 2^23]

__global__ void k_part(const int* __restrict__ src, const int* __restrict__ dst,
                       int* __restrict__ gcnt, u32* __restrict__ gbuf,
                       int e, int Pp, int cap) {
    __shared__ u32 sbuf[PMAX][BCAP];
    __shared__ int scnt[PMAX];
    __shared__ int sbase[PMAX];
    int tid = threadIdx.x;
    int ntile = (e + TILE - 1) / TILE;
    for (int tile = blockIdx.x; tile < ntile; tile += gridDim.x) {
        for (int p = tid; p < Pp; p += 256) scnt[p] = 0;
        __syncthreads();
#pragma unroll
        for (int r = 0; r < TILE / 1024; ++r) {
            int i = tile * TILE + (r * 256 + tid) * 4;
            if (i + 4 <= e) {
                vint4 s4 = __builtin_nontemporal_load((const vint4*)(src + i));
                vint4 d4 = __builtin_nontemporal_load((const vint4*)(dst + i));
#pragma unroll
                for (int k = 0; k < 4; ++k) {
                    int d = d4[k];
                    int p = d >> PSHIFT;
                    u32 pr = ((u32)s4[k] << PSHIFT) | (u32)(d & 511);
                    int pos = atomicAdd(&scnt[p], 1);
                    if (pos < BCAP) sbuf[p][pos] = pr;
                    else {
                        int gp = atomicAdd(&gcnt[p], 1);
                        __builtin_nontemporal_store(pr, &gbuf[(size_t)p * cap + gp]);
                    }
                }
            } else if (i < e) {
                for (int k = i; k < e; ++k) {
                    int d = dst[k];
                    int p = d >> PSHIFT;
                    u32 pr = ((u32)src[k] << PSHIFT) | (u32)(d & 511);
                    int pos = atomicAdd(&scnt[p], 1);
                    if (pos < BCAP) sbuf[p][pos] = pr;
                    else {
                        int gp = atomicAdd(&gcnt[p], 1);
                        __builtin_nontemporal_store(pr, &gbuf[(size_t)p * cap + gp]);
                    }
                }
            }
        }
        __syncthreads();
        for (int p = tid; p < Pp; p += 256)
            sbase[p] = atomicAdd(&gcnt[p], min(scnt[p], BCAP));
        __syncthreads();
        int wid = tid >> 6, lane = tid & 63;
        for (int p = wid; p < Pp; p += 4) {
            int c = min(scnt[p], BCAP);
            int b = sbase[p];
            for (int k = lane; k < c; k += 64)
                __builtin_nontemporal_store(sbuf[p][k], &gbuf[(size_t)p * cap + b + k]);
        }
        __syncthreads();
    }
}

// ---------------- tiny exclusive scan of bucket counts ----------------

__global__ void k_gscan(const int* __restrict__ gcnt, int* __restrict__ gbase, int Pp) {
    __shared__ int s[256];
    int t = threadIdx.x;
    int v = (t < Pp) ? gcnt[t] : 0;
    s[t] = v;
    __syncthreads();
    for (int off = 1; off < 256; off <<= 1) {
        int u = (t >= off) ? s[t - off] : 0;
        __syncthreads();
        s[t] += u;
        __syncthreads();
    }
    if (t < Pp) gbase[t] = s[t] - v;
}

// ---------------- per-partition build: deg/dis/row_ptr/adj (512 thr) --------

__global__ void k_build(const u32* __restrict__ gbuf, const int* __restrict__ gcnt,
                        const int* __restrict__ gbase, int* __restrict__ deg,
                        float* __restrict__ dis, int* __restrict__ row_ptr,
                        int* __restrict__ adj, int cap, int n) {
    __shared__ u32 spairs[SCAP];
    __shared__ int sdeg[512];
    __shared__ int sexcl[512];
    __shared__ int swp[512];
    __shared__ int sscan[512];
    int p = blockIdx.x;
    int tid = threadIdx.x;
    int lo = p << PSHIFT;
    int nn = min(n - lo, 512);
    int cnt = gcnt[p];
    int base = gbase[p];
    const u32* buf = gbuf + (size_t)p * cap;

    sdeg[tid] = 0;
    int scap = min(cnt, SCAP);
    for (int k = tid; k < scap; k += 512)
        spairs[k] = __builtin_nontemporal_load(&buf[k]);
    __syncthreads();
    for (int k = tid; k < cnt; k += 512) {
        u32 pr = (k < SCAP) ? spairs[k] : __builtin_nontemporal_load(&buf[k]);
        atomicAdd(&sdeg[pr & 511], 1);
    }
    __syncthreads();
    int v = sdeg[tid];
    sscan[tid] = v;
    __syncthreads();
    for (int off = 1; off < 512; off <<= 1) {
        int u = (tid >= off) ? sscan[tid - off] : 0;
        __syncthreads();
        sscan[tid] += u;
        __syncthreads();
    }
    sexcl[tid] = sscan[tid] - v;
    swp[tid] = 0;
    __syncthreads();
    if (tid < nn) {
        int dg = sdeg[tid] + 1;
        deg[lo + tid] = dg;
        dis[lo + tid] = rsqrtf((float)dg);
        row_ptr[lo + tid] = base + sexcl[tid];
    }
    for (int k = tid; k < cnt; k += 512) {
        u32 pr = (k < SCAP) ? spairs[k] : __builtin_nontemporal_load(&buf[k]);
        int dl = pr & 511;
        int slot = sexcl[dl] + atomicAdd(&swp[dl], 1);
        adj[base + slot] = (int)(pr >> PSHIFT);
    }
}

// ---------------- legacy fallback ----------------

__global__ void k_count_part(const int* __restrict__ dst, int* __restrict__ deg,
                             int e, int nrange, int n) {
    int g  = blockIdx.x & (NGROUP - 1);
    int lo = g * nrange;
    int hi = min(n, lo + nrange);
    int bid  = blockIdx.x >> 3;
    int nblk = gridDim.x >> 3;
    int i0   = (bid * 256 + threadIdx.x) * 4;
    int step = nblk * 256 * 4;
    for (int i = i0; i < e; i += step) {
        if (i + 4 <= e) {
            int4 d4 = *(const int4*)(dst + i);
            if (d4.x >= lo && d4.x < hi) atomicAdd(&deg[d4.x], 1);
            if (d4.y >= lo && d4.y < hi) atomicAdd(&deg[d4.y], 1);
            if (d4.z >= lo && d4.z < hi) atomicAdd(&deg[d4.z], 1);
            if (d4.w >= lo && d4.w < hi) atomicAdd(&deg[d4.w], 1);
        } else {
            for (int k = i; k < e; ++k) {
                int d = dst[k];
                if (d >= lo && d < hi) atomicAdd(&deg[d], 1);
            }
        }
    }
}

__global__ void k_dis(const int* __restrict__ deg, float* __restrict__ dis, int n) {
    int i = blockIdx.x * 256 + threadIdx.x;
    if (i < n) dis[i] = rsqrtf((float)deg[i]);
}

__global__ void k_scanA(const int* __restrict__ deg, int* __restrict__ row_ptr,
                        int* __restrict__ blksums, int n) {
    __shared__ int s[1024];
    int tid = threadIdx.x;
    int i = blockIdx.x * 1024 + tid;
    int v = (i < n) ? (deg[i] - 1) : 0;
    s[tid] = v;
    __syncthreads();
    for (int off = 1; off < 1024; off <<= 1) {
        int t = (tid >= off) ? s[tid - off] : 0;
        __syncthreads();
        s[tid] += t;
        __syncthreads();
    }
    if (i < n) row_ptr[i] = s[tid] - v;
    if (tid == 1023) blksums[blockIdx.x] = s[1023];
}

__global__ void k_scanB(const int* __restrict__ blksums, int* __restrict__ blkoffs, int nb) {
    __shared__ int s[1024];
    int tid = threadIdx.x;
    int v = (tid < nb) ? blksums[tid] : 0;
    s[tid] = v;
    __syncthreads();
    for (int off = 1; off < 1024; off <<= 1) {
        int t = (tid >= off) ? s[tid - off] : 0;
        __syncthreads();
        s[tid] += t;
        __syncthreads();
    }
    if (tid < nb) blkoffs[tid] = s[tid] - v;
}

__global__ void k_scanC(int* __restrict__ row_ptr, const int* __restrict__ blkoffs,
                        int* __restrict__ write_ptr, int n) {
    int i = blockIdx.x * 1024 + threadIdx.x;
    if (i < n) {
        int r = row_ptr[i] + blkoffs[blockIdx.x];
        row_ptr[i] = r;
        write_ptr[i] = r;
    }
}

__global__ void k_fill_part(const int* __restrict__ src, const int* __restrict__ dst,
                            int* __restrict__ write_ptr, int* __restrict__ adj,
                            int e, int nrange, int n) {
    int g  = blockIdx.x & (NGROUP - 1);
    int lo = g * nrange;
    int hi = min(n, lo + nrange);
    int bid  = blockIdx.x >> 3;
    int nblk = gridDim.x >> 3;
    int i0   = (bid * 256 + threadIdx.x) * 4;
    int step = nblk * 256 * 4;
    for (int i = i0; i < e; i += step) {
        if (i + 4 <= e) {
            int4 d4 = *(const int4*)(dst + i);
            if (d4.x >= lo && d4.x < hi) { int slot = atomicAdd(&write_ptr[d4.x], 1); adj[slot] = src[i];     }
            if (d4.y >= lo && d4.y < hi) { int slot = atomicAdd(&write_ptr[d4.y], 1); adj[slot] = src[i + 1]; }
            if (d4.z >= lo && d4.z < hi) { int slot = atomicAdd(&write_ptr[d4.z], 1); adj[slot] = src[i + 2]; }
            if (d4.w >= lo && d4.w < hi) { int slot = atomicAdd(&write_ptr[d4.w], 1); adj[slot] = src[i + 3]; }
        } else {
            for (int k = i; k < e; ++k) {
                int d = dst[k];
                if (d >= lo && d < hi) { int slot = atomicAdd(&write_ptr[d], 1); adj[slot] = src[k]; }
            }
        }
    }
}

// ---------------- xn = x * dis, padded to 20 floats ----------------

__global__ void k_xn(const float* __restrict__ x, const float* __restrict__ dis,
                     float* __restrict__ xn, int n) {
    int gid = blockIdx.x * 256 + threadIdx.x;
    if (gid >= n * 5) return;
    int i = gid / 5, s = gid - (gid / 5) * 5;
    float dn = dis[i];
    const float* xr = x + (size_t)i * IN_DIM;
    float4 v;
    int k = s * 4;
    v.x = (k + 0 < IN_DIM) ? xr[k + 0] * dn : 0.f;
    v.y = (k + 1 < IN_DIM) ? xr[k + 1] * dn : 0.f;
    v.z = (k + 2 < IN_DIM) ? xr[k + 2] * dn : 0.f;
    v.w = (k + 3 < IN_DIM) ? xr[k + 3] * dn : 0.f;
    *(float4*)(xn + (size_t)i * XPAD + k) = v;
}

// ---------------- fused layer 1+2a: gather + W1 + relu + W2, 16 nodes/block --
// 4 waves x 4 sequential nodes each: weight LDS staging amortized over 16
// nodes (was 4 -> 320MB of redundant weight reads; now 80MB). Per-node gather
// identical to r8: 12 edge-groups x 5 lanes x float4, x2 unroll = 24 in flight.

__global__ void k_agg1f(const float* __restrict__ xn, const int* __restrict__ row_ptr,
                        const int* __restrict__ deg, const int* __restrict__ adj,
                        const float* __restrict__ dis, const float* __restrict__ W1,
                        const float* __restrict__ b1, const float* __restrict__ W2,
                        float* __restrict__ hn2, int n) {
    __shared__ float sw[IN_DIM * HID];
    __shared__ float sw2[HID * EMB];
    __shared__ float sb[HID];
    __shared__ __align__(16) float sagg[4][XPAD];
    __shared__ float sh[4][HID];
    int tid = threadIdx.x;
    for (int t = tid; t < IN_DIM * HID; t += 256) sw[t] = W1[t];
    for (int t = tid; t < HID * EMB; t += 256) sw2[t] = W2[t];
    if (tid < HID) sb[tid] = b1[tid];
    __syncthreads();
    int lane = tid & 63;
    int wv = tid >> 6;
    int eg = lane / 5;               // 0..12 (lanes 60-63 inactive)
    int sl = lane - eg * 5;          // float4 slot 0..4
    bool act = eg < 12;

    for (int nd = wv; nd < NPB; nd += 4) {
        int node = blockIdx.x * NPB + nd;
        if (node >= n) break;        // node uniform per wave
        int beg = row_ptr[node];
        int cnt = deg[node] - 1;
        const int* a = adj + beg;
        float4 acc = make_float4(0.f, 0.f, 0.f, 0.f);
        int base = 0;
        for (; base + 24 <= cnt; base += 24) {
            if (act) {
                int j0 = a[base + eg];
                int j1 = a[base + 12 + eg];
                float4 v0 = *(const float4*)(xn + (size_t)j0 * XPAD + sl * 4);
                float4 v1 = *(const float4*)(xn + (size_t)j1 * XPAD + sl * 4);
                acc.x += v0.x + v1.x; acc.y += v0.y + v1.y;
                acc.z += v0.z + v1.z; acc.w += v0.w + v1.w;
            }
        }
        if (act && base + eg < cnt) {
            float4 v = *(const float4*)(xn + (size_t)a[base + eg] * XPAD + sl * 4);
            acc.x += v.x; acc.y += v.y; acc.z += v.z; acc.w += v.w;
        }
        if (act && base + 12 + eg < cnt) {
            float4 v = *(const float4*)(xn + (size_t)a[base + 12 + eg] * XPAD + sl * 4);
            acc.x += v.x; acc.y += v.y; acc.z += v.z; acc.w += v.w;
        }
        // reduce 12 groups -> group 0
        float4 t = shfl_f4(acc, lane + 30);
        if (lane < 30) { acc.x += t.x; acc.y += t.y; acc.z += t.z; acc.w += t.w; }
        t = shfl_f4(acc, lane + 15);
        if (lane < 15) { acc.x += t.x; acc.y += t.y; acc.z += t.z; acc.w += t.w; }
        t = shfl_f4(acc, lane + 10);
        if (lane < 5) { acc.x += t.x; acc.y += t.y; acc.z += t.z; acc.w += t.w; }
        t = shfl_f4(acc, lane + 5);
        if (lane < 5) { acc.x += t.x; acc.y += t.y; acc.z += t.z; acc.w += t.w; }
        float dn = dis[node];
        if (lane < 5) {
            float4 s4v = *(const float4*)(xn + (size_t)node * XPAD + lane * 4);
            acc.x += s4v.x; acc.y += s4v.y; acc.z += s4v.z; acc.w += s4v.w;
            *(float4*)&sagg[wv][lane * 4] = acc;   // same-wave LDS
        }
        float s = 0.f;
#pragma unroll
        for (int k = 0; k < IN_DIM; ++k) s += sagg[wv][k] * sw[k * HID + lane];
        float hv = dn * s + sb[lane];
        sh[wv][lane] = hv > 0.f ? hv : 0.f;        // h row stays in LDS
        int g = lane & 31, half = lane >> 5;
        float s2 = 0.f;
#pragma unroll
        for (int k = 0; k < 32; ++k)
            s2 += sh[wv][half * 32 + k] * sw2[(half * 32 + k) * EMB + g];
        s2 += __shfl_xor(s2, 32);
        if (half == 0) hn2[(size_t)node * EMB + g] = dn * s2;
    }
}

// ---------------- layer-2 aggregation (float4 per lane, x3 unroll) ----------

__global__ void k_agg2(const float* __restrict__ hn2, const int* __restrict__ row_ptr,
                       const int* __restrict__ deg, const int* __restrict__ adj,
                       const float* __restrict__ dis, const float* __restrict__ b2,
                       float* __restrict__ z, int n) {
    int node = blockIdx.x * 4 + (threadIdx.x >> 6);
    if (node >= n) return;
    int lane = threadIdx.x & 63;
    int eg = lane >> 3;
    int d4 = lane & 7;
    int beg = row_ptr[node];
    int cnt = deg[node] - 1;
    const int* a = adj + beg;
    float4 acc = make_float4(0.f, 0.f, 0.f, 0.f);
    int base = 0;
    for (; base + 24 <= cnt; base += 24) {
        int j0 = a[base + eg];
        int j1 = a[base + 8 + eg];
        int j2 = a[base + 16 + eg];
        float4 v0 = *(const float4*)(hn2 + (size_t)j0 * EMB + d4 * 4);
        float4 v1 = *(const float4*)(hn2 + (size_t)j1 * EMB + d4 * 4);
        float4 v2 = *(const float4*)(hn2 + (size_t)j2 * EMB + d4 * 4);
        acc.x += v0.x + v1.x + v2.x; acc.y += v0.y + v1.y + v2.y;
        acc.z += v0.z + v1.z + v2.z; acc.w += v0.w + v1.w + v2.w;
    }
    int kk = base + eg;
    if (kk < cnt) {
        float4 v = *(const float4*)(hn2 + (size_t)a[kk] * EMB + d4 * 4);
        acc.x += v.x; acc.y += v.y; acc.z += v.z; acc.w += v.w;
    }
    kk += 8;
    if (kk < cnt) {
        float4 v = *(const float4*)(hn2 + (size_t)a[kk] * EMB + d4 * 4);
        acc.x += v.x; acc.y += v.y; acc.z += v.z; acc.w += v.w;
    }
    kk += 8;
    if (kk < cnt) {
        float4 v = *(const float4*)(hn2 + (size_t)a[kk] * EMB + d4 * 4);
        acc.x += v.x; acc.y += v.y; acc.z += v.z; acc.w += v.w;
    }
    float4 t = shfl_xor_f4(acc, 8);
    acc.x += t.x; acc.y += t.y; acc.z += t.z; acc.w += t.w;
    t = shfl_xor_f4(acc, 16);
    acc.x += t.x; acc.y += t.y; acc.z += t.z; acc.w += t.w;
    t = shfl_xor_f4(acc, 32);
    acc.x += t.x; acc.y += t.y; acc.z += t.z; acc.w += t.w;
    if (eg == 0) {
        float4 self = *(const float4*)(hn2 + (size_t)node * EMB + d4 * 4);
        float4 bb = *(const float4*)(b2 + d4 * 4);
        float dn = dis[node];
        float4 o;
        o.x = dn * (acc.x + self.x) + bb.x;
        o.y = dn * (acc.y + self.y) + bb.y;
        o.z = dn * (acc.z + self.z) + bb.z;
        o.w = dn * (acc.w + self.w) + bb.w;
        *(float4*)(z + (size_t)node * EMB + d4 * 4) = o;
    }
}

// ---------------- pair head ----------------

__global__ void k_head(const float* __restrict__ z, const int* __restrict__ tg,
                       const float* __restrict__ Wo, const float* __restrict__ bo,
                       float* __restrict__ out, int btot) {
    int i = blockIdx.x * 256 + threadIdx.x;
    if (i >= btot) return;
    int t0 = tg[i], t1 = tg[btot + i];
    const float* z0 = z + (size_t)t0 * EMB;
    const float* z1 = z + (size_t)t1 * EMB;
    float acc = 0.f;
#pragma unroll
    for (int g = 0; g < EMB; ++g) acc += z0[g] * z1[g] * Wo[g];
    out[i] = acc + bo[0];
}

// ---------------- launch ----------------

extern "C" void kernel_launch(void* const* d_in, const int* in_sizes, int n_in,
                              void* d_out, int out_size, void* d_ws, size_t ws_size,
                              hipStream_t stream) {
    const float* x  = (const float*)d_in[0];
    const int*   ei = (const int*)d_in[1];
    const int*   tg = (const int*)d_in[2];
    const float* W1 = (const float*)d_in[3];
    const float* b1 = (const float*)d_in[4];
    const float* W2 = (const float*)d_in[5];
    const float* b2 = (const float*)d_in[6];
    const float* Wo = (const float*)d_in[7];
    const float* bo = (const float*)d_in[8];
    float* out = (float*)d_out;

    int n = in_sizes[0] / IN_DIM;
    int e = in_sizes[1] / 2;
    int b = in_sizes[2] / 2;
    const int* src = ei;
    const int* dst = ei + e;

    char* ws = (char*)d_ws;
    size_t off = 0;
    auto alloc = [&](size_t bytes) -> char* {
        char* p = ws + off;
        off += (bytes + 255) & ~(size_t)255;
        return p;
    };
    int*   deg       = (int*)alloc((size_t)n * 4);
    int*   row_ptr   = (int*)alloc((size_t)n * 4);
    int*   write_ptr = (int*)alloc((size_t)n * 4);
    int*   blksums   = (int*)alloc(1024 * 4);
    int*   blkoffs   = (int*)alloc(1024 * 4);
    float* dis       = (float*)alloc((size_t)n * 4);
    int*   adj       = (int*)alloc((size_t)e * 4);
    float* xn        = (float*)alloc((size_t)n * XPAD * 4);
    float* bufA      = (float*)alloc((size_t)n * EMB * 4);   // hn2
    float* bufB      = (float*)alloc((size_t)n * EMB * 4);   // z
    int*   gcnt      = (int*)alloc(1024);
    int*   gbase     = (int*)alloc(1024);

    int Pp = (n + 511) >> PSHIFT;
    int meanb = (Pp > 0) ? (e / Pp) : e;
    int cap = meanb + meanb / 16 + 1024;
    size_t bucket_bytes = (size_t)Pp * cap * 4;   // u32 pairs
    bool use_buckets = (Pp <= PMAX) && (n < (1 << 23)) &&
                       ((off + bucket_bytes + 256) <= ws_size);
    u32* gbuf = (u32*)alloc(bucket_bytes);

    int nb1024 = (n + 1023) / 1024;
    int nrange = (n + NGROUP - 1) / NGROUP;

    k_init<<<(n + 255) / 256, 256, 0, stream>>>(deg, gcnt, n);

    if (use_buckets) {
        k_part<<<512, 256, 0, stream>>>(src, dst, gcnt, gbuf, e, Pp, cap);
        k_gscan<<<1, 256, 0, stream>>>(gcnt, gbase, Pp);
        k_build<<<Pp, 512, 0, stream>>>(gbuf, gcnt, gbase, deg, dis, row_ptr, adj, cap, n);
    } else {
        k_count_part<<<2048, 256, 0, stream>>>(dst, deg, e, nrange, n);
        k_dis<<<(n + 255) / 256, 256, 0, stream>>>(deg, dis, n);
        k_scanA<<<nb1024, 1024, 0, stream>>>(deg, row_ptr, blksums, n);
        k_scanB<<<1, 1024, 0, stream>>>(blksums, blkoffs, nb1024);
        k_scanC<<<nb1024, 1024, 0, stream>>>(row_ptr, blkoffs, write_ptr, n);
        k_fill_part<<<2048, 256, 0, stream>>>(src, dst, write_ptr, adj, e, nrange, n);
    }

    k_xn<<<((size_t)n * 5 + 255) / 256, 256, 0, stream>>>(x, dis, xn, n);
    k_agg1f<<<(n + NPB - 1) / NPB, 256, 0, stream>>>(xn, row_ptr, deg, adj, dis, W1, b1, W2, bufA, n);
    k_agg2<<<(n + 3) / 4, 256, 0, stream>>>(bufA, row_ptr, deg, adj, dis, b2, bufB, n);

    k_head<<<(b + 255) / 256, 256, 0, stream>>>(bufB, tg, Wo, bo, out, b);
}